// Round 2
// baseline (128.648 us; speedup 1.0000x reference)
//
#include <hip/hip_runtime.h>

// B = 4194304 samples. x: [B,2] f32, parameters: [B,4] f32, out: [B,2] f32.
//
// Analytic collapse of the 2-qubit circuit (verified vs reference):
//   a = x0+p0, b = x1+p1, c = p2, d = p3   (FULL angles, not half)
//   z0 = cos(a)cos(c) - sin(a)sin(b)sin(c)
//   z1 = cos(a)cos(b)cos(d) - sin(b)sin(d)
// Derivation: RY(d) on q1 is orthogonal within each j0-column, so it preserves
// the per-j0 probability sums feeding <Z0>; expanding the remaining products
// with double-angle identities collapses everything to the two lines above.
//
// Memory plan: 4 samples per thread -> 6x 16B coalesced loads + 2x 16B
// nontemporal stores per lane (output is write-only, don't allocate in L2/L3).

// Native clang ext-vector: __builtin_nontemporal_store requires a vector of
// scalars, not HIP's struct-wrapped float4.
typedef float vfloat4 __attribute__((ext_vector_type(4)));

__device__ __forceinline__ float2 qsample(float x0, float x1, float4 p) {
    float sa, ca, sb, cb, sc, cc, sd, cd;
    __sincosf(x0 + p.x, &sa, &ca);   // a = x0 + p0
    __sincosf(x1 + p.y, &sb, &cb);   // b = x1 + p1
    __sincosf(p.z, &sc, &cc);        // c = p2
    __sincosf(p.w, &sd, &cd);        // d = p3
    float z0 = fmaf(ca, cc, -sa * sb * sc);
    float z1 = fmaf(ca * cb, cd, -sb * sd);
    return make_float2(z0, z1);
}

__global__ void __launch_bounds__(256)
quantum_layer_kernel(const float4* __restrict__ x2,   // [B/2] : 2 samples' x per elem
                     const float4* __restrict__ p4,   // [B]   : 1 sample's params per elem
                     vfloat4* __restrict__ out2,      // [B/2] : 2 samples' (z0,z1) per elem
                     int nquads) {                    // B/4 threads, 4 samples each
    int i = blockIdx.x * blockDim.x + threadIdx.x;
    if (i >= nquads) return;

    // Issue all 6 loads up front (independent, 96B/lane in flight).
    float4 xa = x2[2 * i + 0];   // x0,x1 for samples 0,1
    float4 xb = x2[2 * i + 1];   // x0,x1 for samples 2,3
    float4 pa = p4[4 * i + 0];
    float4 pb = p4[4 * i + 1];
    float4 pc = p4[4 * i + 2];
    float4 pd = p4[4 * i + 3];

    float2 z0 = qsample(xa.x, xa.y, pa);
    float2 z1 = qsample(xa.z, xa.w, pb);
    float2 z2 = qsample(xb.x, xb.y, pc);
    float2 z3 = qsample(xb.z, xb.w, pd);

    vfloat4 o0 = {z0.x, z0.y, z1.x, z1.y};
    vfloat4 o1 = {z2.x, z2.y, z3.x, z3.y};
    __builtin_nontemporal_store(o0, &out2[2 * i + 0]);
    __builtin_nontemporal_store(o1, &out2[2 * i + 1]);
}

extern "C" void kernel_launch(void* const* d_in, const int* in_sizes, int n_in,
                              void* d_out, int out_size, void* d_ws, size_t ws_size,
                              hipStream_t stream) {
    const float4* x2 = (const float4*)d_in[0];   // [B,2] f32 -> B/2 float4
    const float4* p4 = (const float4*)d_in[1];   // [B,4] f32 -> B float4
    vfloat4* out2 = (vfloat4*)d_out;             // [B,2] f32 -> B/2 float4

    int B = in_sizes[0] / 2;     // number of samples (in_sizes counts floats)
    int nquads = B / 4;          // 4 samples per thread
    int block = 256;
    int grid = (nquads + block - 1) / block;
    quantum_layer_kernel<<<grid, block, 0, stream>>>(x2, p4, out2, nquads);
}